// Round 8
// baseline (464.398 us; speedup 1.0000x reference)
//
#include <hip/hip_runtime.h>

#define HDIM 128
#define OFF_SPECIAL 2
#define BSTRIDE 48   // bucket slots per node; deg~Poisson(16), P(deg>=48)~5e-11

typedef __attribute__((ext_vector_type(8))) short bf16x8;
typedef __attribute__((ext_vector_type(4))) float f32x4;

__device__ __forceinline__ float bf2f(unsigned short u) {
    union { unsigned int i; float f; } v;
    v.i = ((unsigned int)u) << 16;
    return v.f;
}
__device__ __forceinline__ unsigned short f2bf(float f) {
    union { float f; unsigned int i; } v;
    v.f = f;
    unsigned int x = v.i;
    x += 0x7FFFu + ((x >> 16) & 1u);   // RNE; data has no NaNs
    return (unsigned short)(x >> 16);
}

#define FILL_BLOCKS 1024   // 128 block-sets x 8 partitions
#define CAST_BLOCKS 512

// --- fused: (a) XCD-partitioned one-pass bucket CSR, (b) emb fp32->bf16 cast.
__global__ void k_fill_cast(const int* __restrict__ src, const int* __restrict__ dst,
                            int E, int* __restrict__ cnt, int* __restrict__ adjB,
                            int partN,
                            const float* __restrict__ emb,
                            unsigned short* __restrict__ embbf, int n4) {
    int tid = threadIdx.x;
    if (blockIdx.x < FILL_BLOCKS) {
        int part = blockIdx.x & 7;
        int blk  = blockIdx.x >> 3;
        int lo = part * partN;
        int hi = lo + partN;            // hi may exceed N; dst < N always
        int stride = (FILL_BLOCKS >> 3) * 256;
        for (int e = blk * 256 + tid; e < E; e += stride) {
            int d = dst[e];
            if (d >= lo && d < hi) {
                int slot = atomicAdd(&cnt[d], 1);
                if (slot < BSTRIDE) adjB[d * BSTRIDE + slot] = src[e];
            }
        }
    } else {
        int i0 = (blockIdx.x - FILL_BLOCKS) * 256 + tid;
        for (int i = i0; i < n4; i += CAST_BLOCKS * 256) {
            float4 v = ((const float4*)emb)[i];
            ushort4 o;
            o.x = f2bf(v.x); o.y = f2bf(v.y); o.z = f2bf(v.z); o.w = f2bf(v.w);
            ((ushort4*)embbf)[i] = o;
        }
    }
}

// --- pull-conv, dual-row per wave for 2x memory-level parallelism.
// agg[r] = x[r]*dinv[r]^2 + sum_nbr x[s]*dinv[s]*dinv[r], dinv computed on the
// fly as rsqrtf(cnt+1). Lane l covers cols 2l,2l+1. Guards keep poisoned bucket
// slots (>deg) from being dereferenced.
__global__ __launch_bounds__(256, 8) void k_pull(
        const unsigned short* __restrict__ x, const int* __restrict__ cnt,
        const int* __restrict__ adjB, unsigned short* __restrict__ agg, int N) {
    int wid = blockIdx.x * 4 + (threadIdx.x >> 6);
    int rA = wid * 2;
    if (rA >= N) return;
    int rB = rA + 1;
    bool hasB = rB < N;
    int lane = threadIdx.x & 63;
    unsigned int cix = 2u * (unsigned int)lane;

    int dA = cnt[rA]; float drA = rsqrtf((float)dA + 1.0f); if (dA > BSTRIDE) dA = BSTRIDE;
    int dB = 0; float drB = 0.f;
    if (hasB) { dB = cnt[rB]; drB = rsqrtf((float)dB + 1.0f); if (dB > BSTRIDE) dB = BSTRIDE; }
    const int* nbrA = adjB + rA * BSTRIDE;
    const int* nbrB = adjB + rB * BSTRIDE;

    float aAx, aAy, aBx = 0.f, aBy = 0.f;
    {
        unsigned int u = *(const unsigned int*)(x + (size_t)(unsigned)rA * HDIM + cix);
        float sc = drA * drA;
        aAx = bf2f((unsigned short)u) * sc;
        aAy = bf2f((unsigned short)(u >> 16)) * sc;
    }
    if (hasB) {
        unsigned int u = *(const unsigned int*)(x + (size_t)(unsigned)rB * HDIM + cix);
        float sc = drB * drB;
        aBx = bf2f((unsigned short)u) * sc;
        aBy = bf2f((unsigned short)(u >> 16)) * sc;
    }

    int m = dA > dB ? dA : dB;
    for (int t = 0; t < m; t += 4) {
        int sA[4], sB[4];
        unsigned int uA[4], uB[4];
        float nrA[4], nrB[4];
        if (t < dA) {   // wave-uniform; int4 slot load (t 16B-aligned, <=44)
            int4 s4 = *(const int4*)(nbrA + t);
            sA[0] = s4.x; sA[1] = s4.y; sA[2] = s4.z; sA[3] = s4.w;
        }
        if (t < dB) {
            int4 s4 = *(const int4*)(nbrB + t);
            sB[0] = s4.x; sB[1] = s4.y; sB[2] = s4.z; sB[3] = s4.w;
        }
#pragma unroll
        for (int i = 0; i < 4; ++i) {
            if (t + i < dA) {
                nrA[i] = rsqrtf((float)cnt[sA[i]] + 1.0f) * drA;
                uA[i] = *(const unsigned int*)(x + (size_t)(unsigned)sA[i] * HDIM + cix);
            }
        }
#pragma unroll
        for (int i = 0; i < 4; ++i) {
            if (t + i < dB) {
                nrB[i] = rsqrtf((float)cnt[sB[i]] + 1.0f) * drB;
                uB[i] = *(const unsigned int*)(x + (size_t)(unsigned)sB[i] * HDIM + cix);
            }
        }
#pragma unroll
        for (int i = 0; i < 4; ++i) {
            if (t + i < dA) {
                aAx = fmaf(bf2f((unsigned short)uA[i]), nrA[i], aAx);
                aAy = fmaf(bf2f((unsigned short)(uA[i] >> 16)), nrA[i], aAy);
            }
        }
#pragma unroll
        for (int i = 0; i < 4; ++i) {
            if (t + i < dB) {
                aBx = fmaf(bf2f((unsigned short)uB[i]), nrB[i], aBx);
                aBy = fmaf(bf2f((unsigned short)(uB[i] >> 16)), nrB[i], aBy);
            }
        }
    }
    unsigned int pA = (unsigned int)f2bf(aAx) | ((unsigned int)f2bf(aAy) << 16);
    *(unsigned int*)(agg + (size_t)(unsigned)rA * HDIM + cix) = pA;
    if (hasB) {
        unsigned int pB = (unsigned int)f2bf(aBx) | ((unsigned int)f2bf(aBy) << 16);
        *(unsigned int*)(agg + (size_t)(unsigned)rB * HDIM + cix) = pB;
    }
}

// --- MFMA GEMM: out[N][128] = A[N][128](bf16) @ W[128][128](fp32->bf16) + b (+ReLU).
// Wave computes a 16-row stripe; 8 col-tiles x 4 K-steps of 16x16x32 MFMA.
// In-place (out==A) safe: each output row depends only on its own input row,
// loaded to registers before any store. Tail overreads stay inside workspace.
template <int RELU>
__global__ __launch_bounds__(256) void k_gemm_mfma(
        const unsigned short* __restrict__ A, const float* __restrict__ W,
        const float* __restrict__ bias, unsigned short* __restrict__ out, int N) {
    __shared__ __align__(16) unsigned short Wt[HDIM * 136];  // [n][k], pad->34.8 KB
    int tid = threadIdx.x;
    for (int i = tid; i < HDIM * HDIM; i += 256) {
        int k = i >> 7, n = i & 127;
        Wt[n * 136 + k] = f2bf(W[i]);   // W[k][n] row-major
    }
    int lane = tid & 63;
    int wv = tid >> 6;
    int n15 = lane & 15, q = lane >> 4;
    float bv[8];
#pragma unroll
    for (int ct = 0; ct < 8; ++ct) bv[ct] = bias[ct * 16 + n15];
    __syncthreads();

    int nChunks = (N + 63) / 64;
    for (int c = blockIdx.x; c < nChunks; c += gridDim.x) {
        int row0 = c * 64 + wv * 16;
        const unsigned short* arow = A + (size_t)(row0 + n15) * HDIM + q * 8;
        bf16x8 a0 = *(const bf16x8*)(arow);
        bf16x8 a1 = *(const bf16x8*)(arow + 32);
        bf16x8 a2 = *(const bf16x8*)(arow + 64);
        bf16x8 a3 = *(const bf16x8*)(arow + 96);
#pragma unroll
        for (int ct = 0; ct < 8; ++ct) {
            const unsigned short* wrow = &Wt[(ct * 16 + n15) * 136 + q * 8];
            f32x4 acc = {0.f, 0.f, 0.f, 0.f};
            acc = __builtin_amdgcn_mfma_f32_16x16x32_bf16(a0, *(const bf16x8*)(wrow),      acc, 0, 0, 0);
            acc = __builtin_amdgcn_mfma_f32_16x16x32_bf16(a1, *(const bf16x8*)(wrow + 32), acc, 0, 0, 0);
            acc = __builtin_amdgcn_mfma_f32_16x16x32_bf16(a2, *(const bf16x8*)(wrow + 64), acc, 0, 0, 0);
            acc = __builtin_amdgcn_mfma_f32_16x16x32_bf16(a3, *(const bf16x8*)(wrow + 96), acc, 0, 0, 0);
#pragma unroll
            for (int r = 0; r < 4; ++r) {
                int row = row0 + q * 4 + r;
                if (row < N) {
                    float v = acc[r] + bv[ct];
                    if (RELU) v = fmaxf(v, 0.0f);
                    out[(size_t)row * HDIM + ct * 16 + n15] = f2bf(v);
                }
            }
        }
    }
}

// --- final gather: out[p] = seq[p]>=0 ? z[seq[p]] (bf16) : emb[seq[p]+2+N] (fp32).
__global__ void k_gather(const int* __restrict__ seq, int P,
                         const unsigned short* __restrict__ z,
                         const float* __restrict__ emb, int N,
                         float* __restrict__ out) {
    int gid = blockIdx.x * blockDim.x + threadIdx.x;
    int p = gid >> 5, c = gid & 31;
    if (p >= P) return;
    int sv = seq[p];
    float4 v;
    if (sv >= 0) {
        uint2 u = *(const uint2*)(z + (size_t)sv * HDIM + c * 4);
        v = make_float4(bf2f((unsigned short)u.x), bf2f((unsigned short)(u.x >> 16)),
                        bf2f((unsigned short)u.y), bf2f((unsigned short)(u.y >> 16)));
    } else {
        v = *(const float4*)(emb + (size_t)(sv + OFF_SPECIAL + N) * HDIM + c * 4);
    }
    *(float4*)(out + (size_t)p * HDIM + c * 4) = v;
}

extern "C" void kernel_launch(void* const* d_in, const int* in_sizes, int n_in,
                              void* d_out, int out_size, void* d_ws, size_t ws_size,
                              hipStream_t stream) {
    const float* emb = (const float*)d_in[0];
    const float* W0  = (const float*)d_in[1];
    const float* b0  = (const float*)d_in[2];
    const float* W1  = (const float*)d_in[3];
    const float* b1  = (const float*)d_in[4];
    const int* ei  = (const int*)d_in[5];
    const int* seq = (const int*)d_in[6];

    int N = in_sizes[0] / HDIM - OFF_SPECIAL;   // 100000
    int E = in_sizes[5] / 2;                    // 1600000
    int P = in_sizes[6];                        // 32768
    const int* srcp = ei;
    const int* dstp = ei + E;

    // workspace: aggbf 25.6 | buf1 (embbf, later hbf) 25.6 | adjB 19.2 | cnt 0.4
    //            => ~70.9 MB
    char* ws = (char*)d_ws;
    size_t off = 0;
    auto alloc = [&](size_t bytes) {
        void* p = ws + off;
        off = (off + bytes + 255) & ~(size_t)255;
        return p;
    };
    unsigned short* aggbf = (unsigned short*)alloc((size_t)N * HDIM * sizeof(unsigned short));
    unsigned short* buf1  = (unsigned short*)alloc((size_t)N * HDIM * sizeof(unsigned short));
    int*   adjB = (int*)alloc((size_t)N * BSTRIDE * sizeof(int));
    int*   cnt  = (int*)alloc((size_t)N * sizeof(int));

    hipMemsetAsync(cnt, 0, (size_t)N * sizeof(int), stream);

    int partN = (N + 7) / 8;
    int n4 = N * HDIM / 4;
    k_fill_cast<<<FILL_BLOCKS + CAST_BLOCKS, 256, 0, stream>>>(
        srcp, dstp, E, cnt, adjB, partN, emb, buf1, n4);

    int pullBlocks = (N + 7) / 8;   // 4 waves/block x 2 rows/wave

    // conv1: pull(embbf=buf1) -> aggbf; MFMA GEMM+ReLU -> hbf (=buf1)
    k_pull<<<pullBlocks, 256, 0, stream>>>(buf1, cnt, adjB, aggbf, N);
    k_gemm_mfma<1><<<640, 256, 0, stream>>>(aggbf, W0, b0, buf1, N);

    // conv2: pull(hbf=buf1) -> aggbf; MFMA GEMM in-place -> z (= aggbf)
    k_pull<<<pullBlocks, 256, 0, stream>>>(buf1, cnt, adjB, aggbf, N);
    k_gemm_mfma<0><<<640, 256, 0, stream>>>(aggbf, W1, b1, aggbf, N);

    // final gather
    k_gather<<<(P * 32 + 255) / 256, 256, 0, stream>>>(seq, P, aggbf, emb, N,
                                                       (float*)d_out);
}

// Round 9
// 394.096 us; speedup vs baseline: 1.1784x; 1.1784x over previous
//
#include <hip/hip_runtime.h>

#define HDIM 128
#define OFF_SPECIAL 2
#define BSTRIDE 48   // bucket slots per node; deg~Poisson(16), P(deg>=48)~5e-11

typedef __attribute__((ext_vector_type(8))) short bf16x8;
typedef __attribute__((ext_vector_type(4))) float f32x4;

__device__ __forceinline__ float bf2f(unsigned short u) {
    union { unsigned int i; float f; } v;
    v.i = ((unsigned int)u) << 16;
    return v.f;
}
__device__ __forceinline__ unsigned short f2bf(float f) {
    union { float f; unsigned int i; } v;
    v.f = f;
    unsigned int x = v.i;
    x += 0x7FFFu + ((x >> 16) & 1u);   // RNE; data has no NaNs
    return (unsigned short)(x >> 16);
}

#define FILL_BLOCKS 1024   // 128 block-sets x 8 partitions
#define CAST_BLOCKS 512

// --- fused: (a) XCD-partitioned one-pass bucket CSR, (b) emb fp32->bf16 cast.
__global__ void k_fill_cast(const int* __restrict__ src, const int* __restrict__ dst,
                            int E, int* __restrict__ cnt, int* __restrict__ adjB,
                            int partN,
                            const float* __restrict__ emb,
                            unsigned short* __restrict__ embbf, int n4) {
    int tid = threadIdx.x;
    if (blockIdx.x < FILL_BLOCKS) {
        int part = blockIdx.x & 7;
        int blk  = blockIdx.x >> 3;
        int lo = part * partN;
        int hi = lo + partN;            // hi may exceed N; dst < N always
        int stride = (FILL_BLOCKS >> 3) * 256;
        for (int e = blk * 256 + tid; e < E; e += stride) {
            int d = dst[e];
            if (d >= lo && d < hi) {
                int slot = atomicAdd(&cnt[d], 1);
                if (slot < BSTRIDE) adjB[d * BSTRIDE + slot] = src[e];
            }
        }
    } else {
        int i0 = (blockIdx.x - FILL_BLOCKS) * 256 + tid;
        for (int i = i0; i < n4; i += CAST_BLOCKS * 256) {
            float4 v = ((const float4*)emb)[i];
            ushort4 o;
            o.x = f2bf(v.x); o.y = f2bf(v.y); o.z = f2bf(v.z); o.w = f2bf(v.w);
            ((ushort4*)embbf)[i] = o;
        }
    }
}

// --- pull-conv: one row per wave; two half-waves process 2 edges concurrently,
// each lane covering 4 cols via one uint2 load (8B). 4-way unroll per half-wave
// -> 8 independent x-row loads in flight, single destination row per wave.
// agg[r] = x[r]*dinv[r]^2 + sum_nbr x[s]*dinv[s]*dinv[r]; dinv = rsqrt(cnt+1).
__global__ __launch_bounds__(256, 8) void k_pull(
        const unsigned short* __restrict__ x, const int* __restrict__ cnt,
        const int* __restrict__ adjB, unsigned short* __restrict__ agg, int N) {
    int row = blockIdx.x * 4 + (threadIdx.x >> 6);
    if (row >= N) return;
    int lane = threadIdx.x & 63;
    int half = lane >> 5;          // 0/1: which edge group this lane serves
    int l16  = lane & 31;          // covers cols 4*l16 .. 4*l16+3
    int d = cnt[row];
    float dr = rsqrtf((float)d + 1.0f);
    if (d > BSTRIDE) d = BSTRIDE;
    const int* nbr = adjB + row * BSTRIDE;
    size_t rowbase = (size_t)(unsigned)row * HDIM;
    unsigned int cix = 4u * (unsigned int)l16;

    float a0 = 0.f, a1 = 0.f, a2 = 0.f, a3 = 0.f;
    if (half == 0) {   // self-loop term, added once
        uint2 u = *(const uint2*)(x + rowbase + cix);
        float sc = dr * dr;
        a0 = bf2f((unsigned short)u.x) * sc;
        a1 = bf2f((unsigned short)(u.x >> 16)) * sc;
        a2 = bf2f((unsigned short)u.y) * sc;
        a3 = bf2f((unsigned short)(u.y >> 16)) * sc;
    }
    for (int t = 0; t < d; t += 8) {
        int base = t + half * 4;   // this half-wave's 4 edges
        int s[4]; uint2 u[4]; float nr[4];
        if (base < d) {            // 16B-aligned int4 slot load (base multiple of 4)
            int4 s4 = *(const int4*)(nbr + base);
            s[0] = s4.x; s[1] = s4.y; s[2] = s4.z; s[3] = s4.w;
        }
#pragma unroll
        for (int i = 0; i < 4; ++i) {
            if (base + i < d) {
                nr[i] = rsqrtf((float)cnt[s[i]] + 1.0f) * dr;
                u[i] = *(const uint2*)(x + (size_t)(unsigned)s[i] * HDIM + cix);
            }
        }
#pragma unroll
        for (int i = 0; i < 4; ++i) {
            if (base + i < d) {
                a0 = fmaf(bf2f((unsigned short)u[i].x), nr[i], a0);
                a1 = fmaf(bf2f((unsigned short)(u[i].x >> 16)), nr[i], a1);
                a2 = fmaf(bf2f((unsigned short)u[i].y), nr[i], a2);
                a3 = fmaf(bf2f((unsigned short)(u[i].y >> 16)), nr[i], a3);
            }
        }
    }
    // merge the two half-wave partial sums
    a0 += __shfl_xor(a0, 32);
    a1 += __shfl_xor(a1, 32);
    a2 += __shfl_xor(a2, 32);
    a3 += __shfl_xor(a3, 32);
    if (half == 0) {
        uint2 p;
        p.x = (unsigned int)f2bf(a0) | ((unsigned int)f2bf(a1) << 16);
        p.y = (unsigned int)f2bf(a2) | ((unsigned int)f2bf(a3) << 16);
        *(uint2*)(agg + rowbase + cix) = p;
    }
}

// --- MFMA GEMM: out[N][128] = A[N][128](bf16) @ W[128][128](fp32->bf16) + b (+ReLU).
// Wave computes a 16-row stripe; 8 col-tiles x 4 K-steps of 16x16x32 MFMA.
// In-place (out==A) safe: each output row depends only on its own input row,
// loaded to registers before any store. Tail overreads stay inside workspace.
template <int RELU>
__global__ __launch_bounds__(256) void k_gemm_mfma(
        const unsigned short* __restrict__ A, const float* __restrict__ W,
        const float* __restrict__ bias, unsigned short* __restrict__ out, int N) {
    __shared__ __align__(16) unsigned short Wt[HDIM * 136];  // [n][k], pad->34.8 KB
    int tid = threadIdx.x;
    for (int i = tid; i < HDIM * HDIM; i += 256) {
        int k = i >> 7, n = i & 127;
        Wt[n * 136 + k] = f2bf(W[i]);   // W[k][n] row-major
    }
    int lane = tid & 63;
    int wv = tid >> 6;
    int n15 = lane & 15, q = lane >> 4;
    float bv[8];
#pragma unroll
    for (int ct = 0; ct < 8; ++ct) bv[ct] = bias[ct * 16 + n15];
    __syncthreads();

    int nChunks = (N + 63) / 64;
    for (int c = blockIdx.x; c < nChunks; c += gridDim.x) {
        int row0 = c * 64 + wv * 16;
        const unsigned short* arow = A + (size_t)(row0 + n15) * HDIM + q * 8;
        bf16x8 a0 = *(const bf16x8*)(arow);
        bf16x8 a1 = *(const bf16x8*)(arow + 32);
        bf16x8 a2 = *(const bf16x8*)(arow + 64);
        bf16x8 a3 = *(const bf16x8*)(arow + 96);
#pragma unroll
        for (int ct = 0; ct < 8; ++ct) {
            const unsigned short* wrow = &Wt[(ct * 16 + n15) * 136 + q * 8];
            f32x4 acc = {0.f, 0.f, 0.f, 0.f};
            acc = __builtin_amdgcn_mfma_f32_16x16x32_bf16(a0, *(const bf16x8*)(wrow),      acc, 0, 0, 0);
            acc = __builtin_amdgcn_mfma_f32_16x16x32_bf16(a1, *(const bf16x8*)(wrow + 32), acc, 0, 0, 0);
            acc = __builtin_amdgcn_mfma_f32_16x16x32_bf16(a2, *(const bf16x8*)(wrow + 64), acc, 0, 0, 0);
            acc = __builtin_amdgcn_mfma_f32_16x16x32_bf16(a3, *(const bf16x8*)(wrow + 96), acc, 0, 0, 0);
#pragma unroll
            for (int r = 0; r < 4; ++r) {
                int row = row0 + q * 4 + r;
                if (row < N) {
                    float v = acc[r] + bv[ct];
                    if (RELU) v = fmaxf(v, 0.0f);
                    out[(size_t)row * HDIM + ct * 16 + n15] = f2bf(v);
                }
            }
        }
    }
}

// --- final gather: out[p] = seq[p]>=0 ? z[seq[p]] (bf16) : emb[seq[p]+2+N] (fp32).
__global__ void k_gather(const int* __restrict__ seq, int P,
                         const unsigned short* __restrict__ z,
                         const float* __restrict__ emb, int N,
                         float* __restrict__ out) {
    int gid = blockIdx.x * blockDim.x + threadIdx.x;
    int p = gid >> 5, c = gid & 31;
    if (p >= P) return;
    int sv = seq[p];
    float4 v;
    if (sv >= 0) {
        uint2 u = *(const uint2*)(z + (size_t)sv * HDIM + c * 4);
        v = make_float4(bf2f((unsigned short)u.x), bf2f((unsigned short)(u.x >> 16)),
                        bf2f((unsigned short)u.y), bf2f((unsigned short)(u.y >> 16)));
    } else {
        v = *(const float4*)(emb + (size_t)(sv + OFF_SPECIAL + N) * HDIM + c * 4);
    }
    *(float4*)(out + (size_t)p * HDIM + c * 4) = v;
}

extern "C" void kernel_launch(void* const* d_in, const int* in_sizes, int n_in,
                              void* d_out, int out_size, void* d_ws, size_t ws_size,
                              hipStream_t stream) {
    const float* emb = (const float*)d_in[0];
    const float* W0  = (const float*)d_in[1];
    const float* b0  = (const float*)d_in[2];
    const float* W1  = (const float*)d_in[3];
    const float* b1  = (const float*)d_in[4];
    const int* ei  = (const int*)d_in[5];
    const int* seq = (const int*)d_in[6];

    int N = in_sizes[0] / HDIM - OFF_SPECIAL;   // 100000
    int E = in_sizes[5] / 2;                    // 1600000
    int P = in_sizes[6];                        // 32768
    const int* srcp = ei;
    const int* dstp = ei + E;

    // workspace: aggbf 25.6 | buf1 (embbf, later hbf) 25.6 | adjB 19.2 | cnt 0.4
    //            => ~70.9 MB
    char* ws = (char*)d_ws;
    size_t off = 0;
    auto alloc = [&](size_t bytes) {
        void* p = ws + off;
        off = (off + bytes + 255) & ~(size_t)255;
        return p;
    };
    unsigned short* aggbf = (unsigned short*)alloc((size_t)N * HDIM * sizeof(unsigned short));
    unsigned short* buf1  = (unsigned short*)alloc((size_t)N * HDIM * sizeof(unsigned short));
    int*   adjB = (int*)alloc((size_t)N * BSTRIDE * sizeof(int));
    int*   cnt  = (int*)alloc((size_t)N * sizeof(int));

    hipMemsetAsync(cnt, 0, (size_t)N * sizeof(int), stream);

    int partN = (N + 7) / 8;
    int n4 = N * HDIM / 4;
    k_fill_cast<<<FILL_BLOCKS + CAST_BLOCKS, 256, 0, stream>>>(
        srcp, dstp, E, cnt, adjB, partN, emb, buf1, n4);

    int pullBlocks = (N + 3) / 4;   // 4 waves/block, 1 row/wave

    // conv1: pull(embbf=buf1) -> aggbf; MFMA GEMM+ReLU -> hbf (=buf1)
    k_pull<<<pullBlocks, 256, 0, stream>>>(buf1, cnt, adjB, aggbf, N);
    k_gemm_mfma<1><<<640, 256, 0, stream>>>(aggbf, W0, b0, buf1, N);

    // conv2: pull(hbf=buf1) -> aggbf; MFMA GEMM in-place -> z (= aggbf)
    k_pull<<<pullBlocks, 256, 0, stream>>>(buf1, cnt, adjB, aggbf, N);
    k_gemm_mfma<0><<<640, 256, 0, stream>>>(aggbf, W1, b1, aggbf, N);

    // final gather
    k_gather<<<(P * 32 + 255) / 256, 256, 0, stream>>>(seq, P, aggbf, emb, N,
                                                       (float*)d_out);
}